// Round 12
// baseline (271.190 us; speedup 1.0000x reference)
//
#include <hip/hip_runtime.h>
#include <hip/hip_bf16.h>
#include <cstdint>

// Problem: x[4,2048,1024] fp32; qkv = x@W_in^T+b_in; 16-head causal attention
// (dh=64); out = attn@W_out^T + b_out -> fp32 [4,2048,1024].
// Verified to date: gemm BK=64 + both-sides XOR swizzle (conflicts->0) + T1
// XCD swizzle (qkv 77 us); flash bare v_exp_f32 + no-M_STATIC exp.
// R16 FAILED: fewer blocks (2/CU) -> flash 116 us. R19 FAILED: forced VGPR 48
// -> spill, 288 us. R20: 64-col swizzle neutral-to-worse (conflicts constant
// 3.2M = staging writes); occupancy stuck at 32% because grid = 1024 blocks
// = exactly 4/CU — no 5th block exists.
// R21 (this): flash restructured to ONE q-tile (64 rows) per block, KVBLK=32
// double-buffered, grid 2048 blocks = 8/CU, LDS 18.4 KB, VGPR ~60 ->
// 32 waves/CU (2x latency hiding). Per-key MFMA/exp/staging identical;
// barrier count doubles but 8 resident blocks hide drains.

typedef float  floatx4  __attribute__((ext_vector_type(4)));
typedef __bf16 bf16x8   __attribute__((ext_vector_type(8)));
typedef __bf16 bf16x4   __attribute__((ext_vector_type(4)));
typedef short  shortx4  __attribute__((ext_vector_type(4)));
typedef unsigned int   uint32x2 __attribute__((ext_vector_type(2)));
typedef unsigned short ushortx8 __attribute__((ext_vector_type(8)));

#define MFMA16(a,b,c) __builtin_amdgcn_mfma_f32_16x16x32_bf16(a, b, c, 0, 0, 0)

// 16x16x16 bf16 MFMA (K=16). Selected only in the device pass (host stub).
__device__ __forceinline__ floatx4 mfma_k16(bf16x4 a, bf16x4 b, floatx4 c) {
#if defined(__HIP_DEVICE_COMPILE__)
#if __has_builtin(__builtin_amdgcn_mfma_f32_16x16x16_bf16)
  return __builtin_amdgcn_mfma_f32_16x16x16_bf16(a, b, c, 0, 0, 0);
#elif __has_builtin(__builtin_amdgcn_mfma_f32_16x16x16bf16_1k)
  return __builtin_amdgcn_mfma_f32_16x16x16bf16_1k(
      __builtin_bit_cast(shortx4, a), __builtin_bit_cast(shortx4, b), c, 0, 0, 0);
#else
  floatx4 d;
  asm("v_mfma_f32_16x16x16_bf16 %0, %1, %2, %3"
      : "=v"(d)
      : "v"(__builtin_bit_cast(uint32x2, a)),
        "v"(__builtin_bit_cast(uint32x2, b)), "v"(c));
  return d;
#endif
#else
  (void)a; (void)b;
  return c;  // host stub
#endif
}

// Bare hardware exp2 (D = 2^S0).
__device__ __forceinline__ float fast_exp2(float x) {
#if defined(__HIP_DEVICE_COMPILE__)
#if __has_builtin(__builtin_amdgcn_exp2f)
  return __builtin_amdgcn_exp2f(x);
#else
  float r;
  asm("v_exp_f32 %0, %1" : "=v"(r) : "v"(x));
  return r;
#endif
#else
  return x;  // host stub
#endif
}

#define C_SCALE 0.18033688011112042f  /* (1/sqrt(64)) * log2(e) */

__device__ __forceinline__ void gload_lds16(const void* g, void* l) {
  __builtin_amdgcn_global_load_lds(
      (__attribute__((address_space(1))) void*)(g),
      (__attribute__((address_space(3))) void*)(l), 16, 0, 0);
}

// ---------------------------------------------------------------- fused casts
#define N_X4    2097152   /* 8192*1024/4 */
#define N_WIN4  786432    /* 3072*1024/4 */
#define N_WOUT4 262144    /* 1024*1024/4 */
#define N_B4    768       /* 3072/4      */
__global__ __launch_bounds__(256) void cast_fused(
    const float* __restrict__ x, const float* __restrict__ W_in,
    const float* __restrict__ W_out, const float* __restrict__ b_in,
    __bf16* __restrict__ xb, __bf16* __restrict__ Winb,
    __bf16* __restrict__ Woutb, float* __restrict__ bins) {
  int i = blockIdx.x * 256 + threadIdx.x;
  if (i < N_X4) {
    const float4 v = ((const float4*)x)[i];
    bf16x4 o;
    o.x = (__bf16)v.x; o.y = (__bf16)v.y; o.z = (__bf16)v.z; o.w = (__bf16)v.w;
    ((bf16x4*)xb)[i] = o;
  } else if (i < N_X4 + N_WIN4) {
    const int j = i - N_X4;
    const float s = (j < 262144) ? C_SCALE : 1.0f;   // first 1024 rows = Q
    const float4 v = ((const float4*)W_in)[j];
    bf16x4 o;
    o.x = (__bf16)(v.x * s); o.y = (__bf16)(v.y * s);
    o.z = (__bf16)(v.z * s); o.w = (__bf16)(v.w * s);
    ((bf16x4*)Winb)[j] = o;
  } else if (i < N_X4 + N_WIN4 + N_WOUT4) {
    const int j = i - N_X4 - N_WIN4;
    const float4 v = ((const float4*)W_out)[j];
    bf16x4 o;
    o.x = (__bf16)v.x; o.y = (__bf16)v.y; o.z = (__bf16)v.z; o.w = (__bf16)v.w;
    ((bf16x4*)Woutb)[j] = o;
  } else {
    const int j = i - N_X4 - N_WIN4 - N_WOUT4;   // 0..767
    const float s = (j < 256) ? C_SCALE : 1.0f;
    float4 v = ((const float4*)b_in)[j];
    v.x *= s; v.y *= s; v.z *= s; v.w *= s;
    ((float4*)bins)[j] = v;
  }
}

// ---------------------------------------------------------------- GEMM C = A @ B^T + bias
// 128x128 tile, BK=64 (32 MFMA per barrier pair). LDS [128][64] per matrix,
// XOR-swizzled; linear gload_lds dest + inverse-swizzled global source col +
// swizzled ds_read col. Verified R6: SQ_LDS_BANK_CONFLICT = 0. T1 XCD block
// swizzle (nwg%8==0): FETCH 71.8 -> 59.4 MB.
// MODE 0: fp32 out. MODE 2: qkv — Q/K cols (<2048) stored bf16 row-major,
// V cols (>=2048) stored transposed into Vt[(b*16+h)*64+dh][s] (8B packed).
template <int MODE>
__global__ __launch_bounds__(256) void gemm_bt(
    const __bf16* __restrict__ A, const __bf16* __restrict__ B,
    const float* __restrict__ bias, void* __restrict__ Cout,
    __bf16* __restrict__ Vt, int M, int N, int K) {
  __shared__ __bf16 As[128 * 64];
  __shared__ __bf16 Bs[128 * 64];
  const int tid = threadIdx.x;
  const int wave = tid >> 6, lane = tid & 63;
  const int quad = lane >> 4, l15 = lane & 15;
  const int wm = (wave & 1) * 64, wn = (wave >> 1) * 64;

  // T1: XCD-contiguous block swizzle (bijective since nwg % 8 == 0)
  const int nwg = (int)(gridDim.x * gridDim.y);
  int f = (int)(blockIdx.y * gridDim.x + blockIdx.x);
  f = (f & 7) * (nwg >> 3) + (f >> 3);
  const int bx = f % (int)gridDim.x;
  const int by = f / (int)gridDim.x;
  const long row0 = (long)by * 128;
  const long col0 = (long)bx * 128;

  floatx4 acc[4][4] = {};

  const int sr = tid >> 3;                         // 0..31
  const int swz = 8 * ((tid & 7) ^ (sr & 7));      // source col (elements)
  const __bf16* ga = A + (row0 + sr) * (long)K + swz;
  const __bf16* gb = B + (col0 + sr) * (long)K + swz;
  __bf16* lA = As + tid * 8;
  __bf16* lB = Bs + tid * 8;
  const int rswz = (l15 & 7) * 8;                  // read-side xor (elements)

  for (int k0 = 0; k0 < K; k0 += 64) {
#pragma unroll
    for (int c = 0; c < 4; ++c) {
      gload_lds16(ga + (long)(32 * c) * K, lA + c * 2048);
      gload_lds16(gb + (long)(32 * c) * K, lB + c * 2048);
    }
    ga += 64; gb += 64;
    __syncthreads();

#pragma unroll
    for (int kh = 0; kh < 2; ++kh) {
      const int kc = (kh * 32 + quad * 8) ^ rswz;
      bf16x8 af[4], bfr[4];
#pragma unroll
      for (int i = 0; i < 4; ++i)
        af[i] = *(const bf16x8*)(As + (wm + i * 16 + l15) * 64 + kc);
#pragma unroll
      for (int j = 0; j < 4; ++j)
        bfr[j] = *(const bf16x8*)(Bs + (wn + j * 16 + l15) * 64 + kc);
#pragma unroll
      for (int i = 0; i < 4; ++i)
#pragma unroll
        for (int j = 0; j < 4; ++j)
          acc[i][j] = MFMA16(af[i], bfr[j], acc[i][j]);
    }
    __syncthreads();
  }

#pragma unroll
  for (int i = 0; i < 4; ++i) {
    const long r0 = row0 + wm + i * 16 + quad * 4;
#pragma unroll
    for (int j = 0; j < 4; ++j) {
      const long c = col0 + wn + j * 16 + l15;
      const float bv = bias[c];
      if (MODE == 0) {
#pragma unroll
        for (int reg = 0; reg < 4; ++reg)
          ((float*)Cout)[(r0 + reg) * (long)N + c] = acc[i][j][reg] + bv;
      } else {
        if (c < 2048) {
#pragma unroll
          for (int reg = 0; reg < 4; ++reg)
            ((__bf16*)Cout)[(r0 + reg) * (long)N + c] =
                (__bf16)(acc[i][j][reg] + bv);
        } else {
          const int cc = (int)c - 2048;
          const int hh = cc >> 6, dh = cc & 63;
          const int bb = (int)(r0 >> 11), s = (int)(r0 & 2047);
          bf16x4 pk;
#pragma unroll
          for (int reg = 0; reg < 4; ++reg)
            pk[reg] = (__bf16)(acc[i][j][reg] + bv);
          *(bf16x4*)(Vt + ((long)(bb * 16 + hh) * 64 + dh) * 2048 + s) = pk;
        }
      }
    }
  }
}

// ---------------------------------------------------------------- flash attention
// ONE q-tile (64 rows) per block; grid (32,16,4) = 2048 blocks = 8/CU.
// KVBLK=32, double-buffered: Ks[2][32*72] ([key][dh], +8 pad) +
// Vs[2][64*36] ([dh][key], +4 pad) = 18.4 KB -> 8 blocks/CU, 32 waves/CU.
// nk = 2*(qt+1) 32-key tiles. Per wave: 16 q-rows; per tile: 4 MFMA K=32
// (QK^T), 2+8 MFMA K=16 (denom+PV), 16 exp. Mask applies when kt >= 2*qt.
// P^T = exp2(S) unnormalized (verified R8); denominator via ones-MFMA.
__global__ __launch_bounds__(256, 8) void flash_attn(
    const __bf16* __restrict__ qkv,   // [8192][3072]
    const __bf16* __restrict__ Vt,    // [64][64][2048]
    __bf16* __restrict__ Out) {       // [8192][1024]
  constexpr int S = 2048;
  const int h = blockIdx.y, b = blockIdx.z;
  const int qt = (int)(blockIdx.x + 5 * blockIdx.z + 3 * blockIdx.y) & 31;
  const int nk = 2 * (qt + 1);        // 32-key tiles (2..64)

  __shared__ __bf16 Ks[2][32 * 72];   // [key][dh+pad]
  __shared__ __bf16 Vs[2][64 * 36];   // [dh][key+pad]

  const int tid = threadIdx.x, wave = tid >> 6, lane = tid & 63;
  const int quad = lane >> 4, l15 = lane & 15;

  // Q frags (B-operand of the S^T MFMA: n=l15, k=quad*8+j)
  bf16x8 qf0, qf1;
  {
    const long qr = (long)(b * S + qt * 64 + wave * 16 + l15) * 3072 + h * 64;
    qf0 = *(const bf16x8*)(qkv + qr + quad * 8);
    qf1 = *(const bf16x8*)(qkv + qr + 32 + quad * 8);
  }

  bf16x4 ones4;
#pragma unroll
  for (int j = 0; j < 4; ++j) ones4[j] = (__bf16)1.0f;

  floatx4 oA[4] = {};                 // O^T C-layout [dh-block]
  floatx4 lA = {0.f, 0.f, 0.f, 0.f};  // denominator

  // staging: K: thread covers key row tid>>3 (0..31), 16B dh chunk (tid&7).
  //          V: thread covers dh row tid>>2 (0..63), 16B key chunk (tid&3).
  const int srow = tid >> 3, sc8 = (tid & 7) * 8;
  const int vd = tid >> 2,  vc8 = (tid & 3) * 8;
  const __bf16* ka = qkv + ((long)(b * S) + srow) * 3072 + 1024 + h * 64 + sc8;
  const __bf16* va = Vt + ((long)(b * 16 + h) * 64 + vd) * S + vc8;
  const int slk = srow * 72 + sc8;
  const int slv = vd * 36 + vc8;

  // prologue: tile 0 -> buf0; prefetch tile 1 into regs (nk >= 2 always)
  ushortx8 kr = *(const ushortx8*)ka;
  ushortx8 vr = *(const ushortx8*)va;
  *(ushortx8*)(&Ks[0][slk]) = kr;
  *(ushortx8*)(&Vs[0][slv]) = vr;
  kr = *(const ushortx8*)(ka + 32 * 3072);
  vr = *(const ushortx8*)(va + 32);
  const __bf16* kn = ka + 64 * 3072;  // tile kt+2 source
  const __bf16* vn = va + 64;
  __syncthreads();

  const int qg = qt * 64 + wave * 16 + l15;   // this lane's q row (global)
  const int wall = qt << 1;                   // first tile needing mask

  for (int kt = 0; kt < nk; ++kt) {
    const int cur = kt & 1;
    if (kt + 1 < nk) {                // prev iter's reads of buf^1 done
      *(ushortx8*)(&Ks[cur ^ 1][slk]) = kr;
      *(ushortx8*)(&Vs[cur ^ 1][slv]) = vr;
    }
    if (kt + 2 < nk) {                // prefetch tile kt+2
      kr = *(const ushortx8*)kn;
      vr = *(const ushortx8*)vn;
      kn += 32 * 3072; vn += 32;
    }

    // S^T = K @ Q^T; mask; P^T = exp2 fused per nb (sv transient)
    bf16x4 pf[2];
    __builtin_amdgcn_s_setprio(1);
#pragma unroll
    for (int nb = 0; nb < 2; ++nb) {
      const int krow = (nb * 16 + l15) * 72;
      const bf16x8 k0 = *(const bf16x8*)(&Ks[cur][krow + quad * 8]);
      const bf16x8 k1 = *(const bf16x8*)(&Ks[cur][krow + 32 + quad * 8]);
      floatx4 z = {0.f, 0.f, 0.f, 0.f};
      z = MFMA16(k0, qf0, z);
      z = MFMA16(k1, qf1, z);
      if (kt >= wall) {               // causal wall band
        const int key0 = kt * 32 + nb * 16 + quad * 4;
#pragma unroll
        for (int r = 0; r < 4; ++r)
          if (key0 + r > qg) z[r] = -1.0e30f;
      }
#pragma unroll
      for (int r = 0; r < 4; ++r)
        pf[nb][r] = (__bf16)fast_exp2(z[r]);
    }
    // denominator via ones-MFMA (matrix pipe)
    lA = mfma_k16(ones4, pf[0], lA);
    lA = mfma_k16(ones4, pf[1], lA);

    // O^T += V^T @ P^T (A = V^T-frag b64 from LDS; B = P^T registers)
#pragma unroll
    for (int mb = 0; mb < 4; ++mb) {
      const int vrow = (mb * 16 + l15) * 36;
#pragma unroll
      for (int c = 0; c < 2; ++c) {
        const bf16x4 vf = *(const bf16x4*)(&Vs[cur][vrow + c * 16 + quad * 4]);
        oA[mb] = mfma_k16(vf, pf[c], oA[mb]);
      }
    }
    __builtin_amdgcn_s_setprio(0);
    __syncthreads();
  }

  // epilogue: lane holds dh = mb*16+quad*4+r at q = l15; denom = lA[0]
  {
    const float inv = 1.f / lA[0];
    const long row = (long)(b * S + qt * 64 + wave * 16 + l15);
#pragma unroll
    for (int mb = 0; mb < 4; ++mb) {
      bf16x4 pk;
#pragma unroll
      for (int r = 0; r < 4; ++r) pk[r] = (__bf16)(oA[mb][r] * inv);
      *(bf16x4*)(Out + row * 1024 + h * 64 + mb * 16 + quad * 4) = pk;
    }
  }
}

// ---------------------------------------------------------------- launch
extern "C" void kernel_launch(void* const* d_in, const int* in_sizes, int n_in,
                              void* d_out, int out_size, void* d_ws, size_t ws_size,
                              hipStream_t stream) {
  const float* x     = (const float*)d_in[0];
  const float* W_in  = (const float*)d_in[1];
  const float* b_in  = (const float*)d_in[2];
  const float* W_out = (const float*)d_in[3];
  const float* b_out = (const float*)d_in[4];

  const int BS = 4 * 2048;   // 8192 rows
  const int D = 1024, N3 = 3072;

  char* w = (char*)d_ws;
  __bf16* xb    = (__bf16*)w;  w += (size_t)BS * D * 2;        // 16 MiB
  __bf16* Winb  = (__bf16*)w;  w += (size_t)N3 * D * 2;        //  6 MiB
  __bf16* Woutb = (__bf16*)w;  w += (size_t)D * D * 2;         //  2 MiB
  __bf16* qkvb  = (__bf16*)w;  w += (size_t)BS * N3 * 2;       // 48 MiB
  __bf16* Vtb   = (__bf16*)w;  w += (size_t)64 * 64 * 2048 * 2;// 16 MiB
  __bf16* attnb = (__bf16*)w;  w += (size_t)BS * D * 2;        // 16 MiB
  float*  bins  = (float*)w;   w += (size_t)N3 * 4;            // 12 KiB

  const int castN = N_X4 + N_WIN4 + N_WOUT4 + N_B4;            // 3146496
  cast_fused<<<dim3(castN / 256), 256, 0, stream>>>(
      x, W_in, W_out, b_in, xb, Winb, Woutb, bins);

  gemm_bt<2><<<dim3(N3 / 128, BS / 128), 256, 0, stream>>>(
      xb, Winb, bins, (void*)qkvb, Vtb, BS, N3, D);

  flash_attn<<<dim3(32, 16, 4), 256, 0, stream>>>(qkvb, Vtb, attnb);

  gemm_bt<0><<<dim3(D / 128, BS / 128), 256, 0, stream>>>(
      attnb, Woutb, b_out, d_out, nullptr, BS, D, D);
}

// Round 13
// 248.194 us; speedup vs baseline: 1.0927x; 1.0927x over previous
//
#include <hip/hip_runtime.h>
#include <hip/hip_bf16.h>
#include <cstdint>

// Problem: x[4,2048,1024] fp32; qkv = x@W_in^T+b_in; 16-head causal attention
// (dh=64); out = attn@W_out^T + b_out -> fp32 [4,2048,1024].
// Verified: gemm BK=64 + both-sides XOR swizzle (conflicts->0) + T1 XCD
// swizzle (qkv 77 us). Flash occupancy ladder: 2/CU->116, 4/CU->77 (best),
// 8/CU-VGPR-starved->90. R20 vs R6: conflicts constant 3.2M across read
// layouts -> they are the staging DS_WRITES. Both pipes ~40% idle at 77 us
// -> reg-staging path is the stall.
// R22: flash staging via global_load_lds (gemm-proven pattern): linear
// [64][64] LDS dest, inverse-XOR-swizzled GLOBAL source col, R20-proven
// read-side XOR. Kills ds_writes (conflicts -> ~0), frees ~16 VGPR, loads
// for tile kt+1 issued at iter-top overlap full compute phase; the
// vmcnt(0) in __syncthreads() fences completion. 2-set, 4 blocks/CU.

typedef float  floatx4  __attribute__((ext_vector_type(4)));
typedef __bf16 bf16x8   __attribute__((ext_vector_type(8)));
typedef __bf16 bf16x4   __attribute__((ext_vector_type(4)));
typedef short  shortx4  __attribute__((ext_vector_type(4)));
typedef unsigned int   uint32x2 __attribute__((ext_vector_type(2)));
typedef unsigned short ushortx8 __attribute__((ext_vector_type(8)));

#define MFMA16(a,b,c) __builtin_amdgcn_mfma_f32_16x16x32_bf16(a, b, c, 0, 0, 0)

// 16x16x16 bf16 MFMA (K=16). Selected only in the device pass (host stub).
__device__ __forceinline__ floatx4 mfma_k16(bf16x4 a, bf16x4 b, floatx4 c) {
#if defined(__HIP_DEVICE_COMPILE__)
#if __has_builtin(__builtin_amdgcn_mfma_f32_16x16x16_bf16)
  return __builtin_amdgcn_mfma_f32_16x16x16_bf16(a, b, c, 0, 0, 0);
#elif __has_builtin(__builtin_amdgcn_mfma_f32_16x16x16bf16_1k)
  return __builtin_amdgcn_mfma_f32_16x16x16bf16_1k(
      __builtin_bit_cast(shortx4, a), __builtin_bit_cast(shortx4, b), c, 0, 0, 0);
#else
  floatx4 d;
  asm("v_mfma_f32_16x16x16_bf16 %0, %1, %2, %3"
      : "=v"(d)
      : "v"(__builtin_bit_cast(uint32x2, a)),
        "v"(__builtin_bit_cast(uint32x2, b)), "v"(c));
  return d;
#endif
#else
  (void)a; (void)b;
  return c;  // host stub
#endif
}

// Bare hardware exp2 (D = 2^S0).
__device__ __forceinline__ float fast_exp2(float x) {
#if defined(__HIP_DEVICE_COMPILE__)
#if __has_builtin(__builtin_amdgcn_exp2f)
  return __builtin_amdgcn_exp2f(x);
#else
  float r;
  asm("v_exp_f32 %0, %1" : "=v"(r) : "v"(x));
  return r;
#endif
#else
  return x;  // host stub
#endif
}

#define C_SCALE 0.18033688011112042f  /* (1/sqrt(64)) * log2(e) */

__device__ __forceinline__ void gload_lds16(const void* g, void* l) {
  __builtin_amdgcn_global_load_lds(
      (__attribute__((address_space(1))) void*)(g),
      (__attribute__((address_space(3))) void*)(l), 16, 0, 0);
}

// ---------------------------------------------------------------- fused casts
#define N_X4    2097152   /* 8192*1024/4 */
#define N_WIN4  786432    /* 3072*1024/4 */
#define N_WOUT4 262144    /* 1024*1024/4 */
#define N_B4    768       /* 3072/4      */
__global__ __launch_bounds__(256) void cast_fused(
    const float* __restrict__ x, const float* __restrict__ W_in,
    const float* __restrict__ W_out, const float* __restrict__ b_in,
    __bf16* __restrict__ xb, __bf16* __restrict__ Winb,
    __bf16* __restrict__ Woutb, float* __restrict__ bins) {
  int i = blockIdx.x * 256 + threadIdx.x;
  if (i < N_X4) {
    const float4 v = ((const float4*)x)[i];
    bf16x4 o;
    o.x = (__bf16)v.x; o.y = (__bf16)v.y; o.z = (__bf16)v.z; o.w = (__bf16)v.w;
    ((bf16x4*)xb)[i] = o;
  } else if (i < N_X4 + N_WIN4) {
    const int j = i - N_X4;
    const float s = (j < 262144) ? C_SCALE : 1.0f;   // first 1024 rows = Q
    const float4 v = ((const float4*)W_in)[j];
    bf16x4 o;
    o.x = (__bf16)(v.x * s); o.y = (__bf16)(v.y * s);
    o.z = (__bf16)(v.z * s); o.w = (__bf16)(v.w * s);
    ((bf16x4*)Winb)[j] = o;
  } else if (i < N_X4 + N_WIN4 + N_WOUT4) {
    const int j = i - N_X4 - N_WIN4;
    const float4 v = ((const float4*)W_out)[j];
    bf16x4 o;
    o.x = (__bf16)v.x; o.y = (__bf16)v.y; o.z = (__bf16)v.z; o.w = (__bf16)v.w;
    ((bf16x4*)Woutb)[j] = o;
  } else {
    const int j = i - N_X4 - N_WIN4 - N_WOUT4;   // 0..767
    const float s = (j < 256) ? C_SCALE : 1.0f;
    float4 v = ((const float4*)b_in)[j];
    v.x *= s; v.y *= s; v.z *= s; v.w *= s;
    ((float4*)bins)[j] = v;
  }
}

// ---------------------------------------------------------------- GEMM C = A @ B^T + bias
// 128x128 tile, BK=64 (32 MFMA per barrier pair). LDS [128][64] per matrix,
// XOR-swizzled; linear gload_lds dest + inverse-swizzled global source col +
// swizzled ds_read col. Verified R6: SQ_LDS_BANK_CONFLICT = 0. T1 XCD block
// swizzle (nwg%8==0): FETCH 71.8 -> 59.4 MB.
// MODE 0: fp32 out. MODE 2: qkv — Q/K cols (<2048) stored bf16 row-major,
// V cols (>=2048) stored transposed into Vt[(b*16+h)*64+dh][s] (8B packed).
template <int MODE>
__global__ __launch_bounds__(256) void gemm_bt(
    const __bf16* __restrict__ A, const __bf16* __restrict__ B,
    const float* __restrict__ bias, void* __restrict__ Cout,
    __bf16* __restrict__ Vt, int M, int N, int K) {
  __shared__ __bf16 As[128 * 64];
  __shared__ __bf16 Bs[128 * 64];
  const int tid = threadIdx.x;
  const int wave = tid >> 6, lane = tid & 63;
  const int quad = lane >> 4, l15 = lane & 15;
  const int wm = (wave & 1) * 64, wn = (wave >> 1) * 64;

  // T1: XCD-contiguous block swizzle (bijective since nwg % 8 == 0)
  const int nwg = (int)(gridDim.x * gridDim.y);
  int f = (int)(blockIdx.y * gridDim.x + blockIdx.x);
  f = (f & 7) * (nwg >> 3) + (f >> 3);
  const int bx = f % (int)gridDim.x;
  const int by = f / (int)gridDim.x;
  const long row0 = (long)by * 128;
  const long col0 = (long)bx * 128;

  floatx4 acc[4][4] = {};

  const int sr = tid >> 3;                         // 0..31
  const int swz = 8 * ((tid & 7) ^ (sr & 7));      // source col (elements)
  const __bf16* ga = A + (row0 + sr) * (long)K + swz;
  const __bf16* gb = B + (col0 + sr) * (long)K + swz;
  __bf16* lA = As + tid * 8;
  __bf16* lB = Bs + tid * 8;
  const int rswz = (l15 & 7) * 8;                  // read-side xor (elements)

  for (int k0 = 0; k0 < K; k0 += 64) {
#pragma unroll
    for (int c = 0; c < 4; ++c) {
      gload_lds16(ga + (long)(32 * c) * K, lA + c * 2048);
      gload_lds16(gb + (long)(32 * c) * K, lB + c * 2048);
    }
    ga += 64; gb += 64;
    __syncthreads();

#pragma unroll
    for (int kh = 0; kh < 2; ++kh) {
      const int kc = (kh * 32 + quad * 8) ^ rswz;
      bf16x8 af[4], bfr[4];
#pragma unroll
      for (int i = 0; i < 4; ++i)
        af[i] = *(const bf16x8*)(As + (wm + i * 16 + l15) * 64 + kc);
#pragma unroll
      for (int j = 0; j < 4; ++j)
        bfr[j] = *(const bf16x8*)(Bs + (wn + j * 16 + l15) * 64 + kc);
#pragma unroll
      for (int i = 0; i < 4; ++i)
#pragma unroll
        for (int j = 0; j < 4; ++j)
          acc[i][j] = MFMA16(af[i], bfr[j], acc[i][j]);
    }
    __syncthreads();
  }

#pragma unroll
  for (int i = 0; i < 4; ++i) {
    const long r0 = row0 + wm + i * 16 + quad * 4;
#pragma unroll
    for (int j = 0; j < 4; ++j) {
      const long c = col0 + wn + j * 16 + l15;
      const float bv = bias[c];
      if (MODE == 0) {
#pragma unroll
        for (int reg = 0; reg < 4; ++reg)
          ((float*)Cout)[(r0 + reg) * (long)N + c] = acc[i][j][reg] + bv;
      } else {
        if (c < 2048) {
#pragma unroll
          for (int reg = 0; reg < 4; ++reg)
            ((__bf16*)Cout)[(r0 + reg) * (long)N + c] =
                (__bf16)(acc[i][j][reg] + bv);
        } else {
          const int cc = (int)c - 2048;
          const int hh = cc >> 6, dh = cc & 63;
          const int bb = (int)(r0 >> 11), s = (int)(r0 & 2047);
          bf16x4 pk;
#pragma unroll
          for (int reg = 0; reg < 4; ++reg)
            pk[reg] = (__bf16)(acc[i][j][reg] + bv);
          *(bf16x4*)(Vt + ((long)(bb * 16 + hh) * 64 + dh) * 2048 + s) = pk;
        }
      }
    }
  }
}

// ---------------------------------------------------------------- flash attention
// Block = (swizzled x, h, b), 256 thr (4 waves), grid 1024 = 4 blocks/CU
// (proven-best occupancy). q-tiles qtA=x, qtB=31-x share one K-loop.
// K/V staged via global_load_lds into linear [64][64] LDS (32 KB total),
// content-swizzled via inverse-XOR on the GLOBAL source col (rule #21;
// gemm-verified involution); reads use the R20-proven XOR formulas.
// Loads for tile kt+1 issue at iter-top into buf^1 (barrier at end of kt-1
// drained its readers); __syncthreads()'s vmcnt(0) fences completion.
// S^T = K@Q^T; P^T = exp2(S) unnormalized (verified R8); denom via
// ones-MFMA; O^T += V^T-frag @ P^T.
__global__ __launch_bounds__(256, 4) void flash_attn(
    const __bf16* __restrict__ qkv,   // [8192][3072]
    const __bf16* __restrict__ Vt,    // [64][64][2048]
    __bf16* __restrict__ Out) {       // [8192][1024]
  constexpr int S = 2048;
  const int h = blockIdx.y, b = blockIdx.z;
  const int x = (int)(blockIdx.x + 5 * blockIdx.z + 3 * blockIdx.y) & 15;
  const int qtA = x, qtB = 31 - x;
  const int kmaxA = qtA + 1;
  const int kmax  = qtB + 1;          // wall iterations (17..32)

  __shared__ __bf16 Ks[2][64 * 64];
  __shared__ __bf16 Vs[2][64 * 64];   // [dh][key]

  const int tid = threadIdx.x, wave = tid >> 6, lane = tid & 63;
  const int quad = lane >> 4, l15 = lane & 15;

  // Q frags (B-operand of the S^T MFMA: n=l15, k=quad*8+j)
  bf16x8 qf[2][2];
  {
    const long qrA = (long)(b * S + qtA * 64 + wave * 16 + l15) * 3072 + h * 64;
    const long qrB = (long)(b * S + qtB * 64 + wave * 16 + l15) * 3072 + h * 64;
    qf[0][0] = *(const bf16x8*)(qkv + qrA + quad * 8);
    qf[0][1] = *(const bf16x8*)(qkv + qrA + 32 + quad * 8);
    qf[1][0] = *(const bf16x8*)(qkv + qrB + quad * 8);
    qf[1][1] = *(const bf16x8*)(qkv + qrB + 32 + quad * 8);
  }

  bf16x4 ones4;
#pragma unroll
  for (int j = 0; j < 4; ++j) ones4[j] = (__bf16)1.0f;

  floatx4 oA[4] = {}, oB[4] = {};     // O^T C-layout
  floatx4 lA = {0.f, 0.f, 0.f, 0.f}, lB = {0.f, 0.f, 0.f, 0.f};

  // staging (global_load_lds): thread covers rows r and r+32, 16B chunk
  // tid&7; LDS dest linear tid*16B; source col inverse-swizzled.
  // (r+32)&7 == r&7, so one swizzle serves both row-replicas.
  const int r = tid >> 3;                          // 0..31
  const int csw = 8 * ((tid & 7) ^ (r & 7));       // source col (elements)
  const __bf16* ka = qkv + ((long)(b * S) + r) * 3072 + 1024 + h * 64 + csw;
  const __bf16* va = Vt + ((long)(b * 16 + h) * 64 + r) * S + csw;

  // prologue: tile 0 -> buf0
  gload_lds16(ka,                 &Ks[0][tid * 8]);
  gload_lds16(ka + 32 * 3072,     &Ks[0][tid * 8 + 32 * 64]);
  gload_lds16(va,                 &Vs[0][tid * 8]);
  gload_lds16(va + 32 * (long)S,  &Vs[0][tid * 8 + 32 * 64]);
  const __bf16* kan = ka + 64 * 3072;  // tile kt+1 source
  const __bf16* van = va + 64;
  __syncthreads();

  const int rs = (l15 & 7) * 8;       // read-side xor (elements)

  for (int kt = 0; kt < kmax; ++kt) {
    const int cur = kt & 1;
    if (kt + 1 < kmax) {              // issue next tile into buf^1
      gload_lds16(kan,                &Ks[cur ^ 1][tid * 8]);
      gload_lds16(kan + 32 * 3072,    &Ks[cur ^ 1][tid * 8 + 32 * 64]);
      gload_lds16(van,                &Vs[cur ^ 1][tid * 8]);
      gload_lds16(van + 32 * (long)S, &Vs[cur ^ 1][tid * 8 + 32 * 64]);
      kan += 64 * 3072; van += 64;
    }

    const bool actA = (kt < kmaxA);
    const bool partA = (kt == qtA);
    const bool partB = (kt == qtB);

    // S^T = K @ Q^T for both sets, sharing each K fragment read
    floatx4 svA[4], svB[4];
    __builtin_amdgcn_s_setprio(1);
#pragma unroll
    for (int nb = 0; nb < 4; ++nb) {
      const int krow = (nb * 16 + l15) * 64;
      const bf16x8 k0 = *(const bf16x8*)(&Ks[cur][krow + ((quad * 8) ^ rs)]);
      const bf16x8 k1 = *(const bf16x8*)(&Ks[cur][krow + ((32 + quad * 8) ^ rs)]);
      if (actA) {
        floatx4 z = {0.f, 0.f, 0.f, 0.f};
        z = MFMA16(k0, qf[0][0], z);
        z = MFMA16(k1, qf[0][1], z);
        svA[nb] = z;
      }
      {
        floatx4 z = {0.f, 0.f, 0.f, 0.f};
        z = MFMA16(k0, qf[1][0], z);
        z = MFMA16(k1, qf[1][1], z);
        svB[nb] = z;
      }
    }
    __builtin_amdgcn_s_setprio(0);

    // causal mask on S^T: key = kt*64+nb*16+quad*4+r, q = qt*64+wave*16+l15
    if (partA) {
      const int qg = qtA * 64 + wave * 16 + l15;
#pragma unroll
      for (int nb = 0; nb < 4; ++nb) {
        const int key0 = kt * 64 + nb * 16 + quad * 4;
#pragma unroll
        for (int rr = 0; rr < 4; ++rr)
          if (key0 + rr > qg) svA[nb][rr] = -1.0e30f;
      }
    }
    if (partB) {
      const int qg = qtB * 64 + wave * 16 + l15;
#pragma unroll
      for (int nb = 0; nb < 4; ++nb) {
        const int key0 = kt * 64 + nb * 16 + quad * 4;
#pragma unroll
        for (int rr = 0; rr < 4; ++rr)
          if (key0 + rr > qg) svB[nb][rr] = -1.0e30f;
      }
    }

    // P^T = exp2(S^T) packed bf16x4 (unnormalized; denominator absorbs it)
    bf16x4 pfA[4], pfB[4];
    if (actA) {
#pragma unroll
      for (int nb = 0; nb < 4; ++nb)
#pragma unroll
        for (int rr = 0; rr < 4; ++rr)
          pfA[nb][rr] = (__bf16)fast_exp2(svA[nb][rr]);
#pragma unroll
      for (int c = 0; c < 4; ++c) lA = mfma_k16(ones4, pfA[c], lA);
    }
    {
#pragma unroll
      for (int nb = 0; nb < 4; ++nb)
#pragma unroll
        for (int rr = 0; rr < 4; ++rr)
          pfB[nb][rr] = (__bf16)fast_exp2(svB[nb][rr]);
#pragma unroll
      for (int c = 0; c < 4; ++c) lB = mfma_k16(ones4, pfB[c], lB);
    }

    // O^T += V^T @ P^T (A = V^T-frag b64 from LDS, shared; B = P^T registers)
    __builtin_amdgcn_s_setprio(1);
#pragma unroll
    for (int mb = 0; mb < 4; ++mb) {
      const int vrow = (mb * 16 + l15) * 64;
#pragma unroll
      for (int c = 0; c < 4; ++c) {
        const int vcol = c * 16 + quad * 4;
        const int vphys = (((vcol >> 3) ^ (l15 & 7)) << 3) + (vcol & 7);
        const bf16x4 vf = *(const bf16x4*)(&Vs[cur][vrow + vphys]);
        if (actA) oA[mb] = mfma_k16(vf, pfA[c], oA[mb]);
        oB[mb] = mfma_k16(vf, pfB[c], oB[mb]);
      }
    }
    __builtin_amdgcn_s_setprio(0);
    __syncthreads();                  // vmcnt(0) drain fences next-tile loads
  }

  // epilogue: lane holds dh = mb*16+quad*4+r at q = l15; denom = lX[0]
  {
    const float inv = 1.f / lA[0];
    const long row = (long)(b * S + qtA * 64 + wave * 16 + l15);
#pragma unroll
    for (int mb = 0; mb < 4; ++mb) {
      bf16x4 pk;
#pragma unroll
      for (int rr = 0; rr < 4; ++rr) pk[rr] = (__bf16)(oA[mb][rr] * inv);
      *(bf16x4*)(Out + row * 1024 + h * 64 + mb * 16 + quad * 4) = pk;
    }
  }
  {
    const float inv = 1.f / lB[0];
    const long row = (long)(b * S + qtB * 64 + wave * 16 + l15);
#pragma unroll
    for (int mb = 0; mb < 4; ++mb) {
      bf16x4 pk;
#pragma unroll
      for (int rr = 0; rr < 4; ++rr) pk[rr] = (__bf16)(oB[mb][rr] * inv);
      *(bf16x4*)(Out + row * 1024 + h * 64 + mb * 16 + quad * 4) = pk;
    }
  }
}

// ---------------------------------------------------------------- launch
extern "C" void kernel_launch(void* const* d_in, const int* in_sizes, int n_in,
                              void* d_out, int out_size, void* d_ws, size_t ws_size,
                              hipStream_t stream) {
  const float* x     = (const float*)d_in[0];
  const float* W_in  = (const float*)d_in[1];
  const float* b_in  = (const float*)d_in[2];
  const float* W_out = (const float*)d_in[3];
  const float* b_out = (const float*)d_in[4];

  const int BS = 4 * 2048;   // 8192 rows
  const int D = 1024, N3 = 3072;

  char* w = (char*)d_ws;
  __bf16* xb    = (__bf16*)w;  w += (size_t)BS * D * 2;        // 16 MiB
  __bf16* Winb  = (__bf16*)w;  w += (size_t)N3 * D * 2;        //  6 MiB
  __bf16* Woutb = (__bf16*)w;  w += (size_t)D * D * 2;         //  2 MiB
  __bf16* qkvb  = (__bf16*)w;  w += (size_t)BS * N3 * 2;       // 48 MiB
  __bf16* Vtb   = (__bf16*)w;  w += (size_t)64 * 64 * 2048 * 2;// 16 MiB
  __bf16* attnb = (__bf16*)w;  w += (size_t)BS * D * 2;        // 16 MiB
  float*  bins  = (float*)w;   w += (size_t)N3 * 4;            // 12 KiB

  const int castN = N_X4 + N_WIN4 + N_WOUT4 + N_B4;            // 3146496
  cast_fused<<<dim3(castN / 256), 256, 0, stream>>>(
      x, W_in, W_out, b_in, xb, Winb, Woutb, bins);

  gemm_bt<2><<<dim3(N3 / 128, BS / 128), 256, 0, stream>>>(
      xb, Winb, bins, (void*)qkvb, Vtb, BS, N3, D);

  flash_attn<<<dim3(16, 16, 4), 256, 0, stream>>>(qkvb, Vtb, attnb);

  gemm_bt<0><<<dim3(D / 128, BS / 128), 256, 0, stream>>>(
      attnb, Woutb, b_out, d_out, nullptr, BS, D, D);
}

// Round 14
// 246.370 us; speedup vs baseline: 1.1007x; 1.0074x over previous
//
#include <hip/hip_runtime.h>
#include <hip/hip_bf16.h>
#include <cstdint>

// Problem: x[4,2048,1024] fp32; qkv = x@W_in^T+b_in; 16-head causal attention
// (dh=64); out = attn@W_out^T + b_out -> fp32 [4,2048,1024].
// Verified: gemm BK=64 + both-sides XOR swizzle (conflicts 0) + T1 XCD
// swizzle. R22 (measured R13, total 248.2): flash staged via global_load_lds,
// single barrier/iter, loads issued before compute -> flash <70 us.
// R23 (this): apply the SAME proven pattern to gemm_bt — the current loop
// barriers immediately after issuing gload_lds, exposing full HBM latency
// every iter (MfmaUtil 30%). Double-buffer LDS (64 KB, 2 blocks/CU = same
// 8 waves/CU as measured residency), stage tile kt+1 into buf^1 before
// computing buf[cur], ONE __syncthreads() per iter (vmcnt(0) fences stage,
// exec-sync fences reads). T3-minimum-2-phase; m248v2: ~90% of full 8-phase.

typedef float  floatx4  __attribute__((ext_vector_type(4)));
typedef __bf16 bf16x8   __attribute__((ext_vector_type(8)));
typedef __bf16 bf16x4   __attribute__((ext_vector_type(4)));
typedef short  shortx4  __attribute__((ext_vector_type(4)));
typedef unsigned int   uint32x2 __attribute__((ext_vector_type(2)));
typedef unsigned short ushortx8 __attribute__((ext_vector_type(8)));

#define MFMA16(a,b,c) __builtin_amdgcn_mfma_f32_16x16x32_bf16(a, b, c, 0, 0, 0)

// 16x16x16 bf16 MFMA (K=16). Selected only in the device pass (host stub).
__device__ __forceinline__ floatx4 mfma_k16(bf16x4 a, bf16x4 b, floatx4 c) {
#if defined(__HIP_DEVICE_COMPILE__)
#if __has_builtin(__builtin_amdgcn_mfma_f32_16x16x16_bf16)
  return __builtin_amdgcn_mfma_f32_16x16x16_bf16(a, b, c, 0, 0, 0);
#elif __has_builtin(__builtin_amdgcn_mfma_f32_16x16x16bf16_1k)
  return __builtin_amdgcn_mfma_f32_16x16x16bf16_1k(
      __builtin_bit_cast(shortx4, a), __builtin_bit_cast(shortx4, b), c, 0, 0, 0);
#else
  floatx4 d;
  asm("v_mfma_f32_16x16x16_bf16 %0, %1, %2, %3"
      : "=v"(d)
      : "v"(__builtin_bit_cast(uint32x2, a)),
        "v"(__builtin_bit_cast(uint32x2, b)), "v"(c));
  return d;
#endif
#else
  (void)a; (void)b;
  return c;  // host stub
#endif
}

// Bare hardware exp2 (D = 2^S0).
__device__ __forceinline__ float fast_exp2(float x) {
#if defined(__HIP_DEVICE_COMPILE__)
#if __has_builtin(__builtin_amdgcn_exp2f)
  return __builtin_amdgcn_exp2f(x);
#else
  float r;
  asm("v_exp_f32 %0, %1" : "=v"(r) : "v"(x));
  return r;
#endif
#else
  return x;  // host stub
#endif
}

#define C_SCALE 0.18033688011112042f  /* (1/sqrt(64)) * log2(e) */

__device__ __forceinline__ void gload_lds16(const void* g, void* l) {
  __builtin_amdgcn_global_load_lds(
      (__attribute__((address_space(1))) void*)(g),
      (__attribute__((address_space(3))) void*)(l), 16, 0, 0);
}

// ---------------------------------------------------------------- fused casts
#define N_X4    2097152   /* 8192*1024/4 */
#define N_WIN4  786432    /* 3072*1024/4 */
#define N_WOUT4 262144    /* 1024*1024/4 */
#define N_B4    768       /* 3072/4      */
__global__ __launch_bounds__(256) void cast_fused(
    const float* __restrict__ x, const float* __restrict__ W_in,
    const float* __restrict__ W_out, const float* __restrict__ b_in,
    __bf16* __restrict__ xb, __bf16* __restrict__ Winb,
    __bf16* __restrict__ Woutb, float* __restrict__ bins) {
  int i = blockIdx.x * 256 + threadIdx.x;
  if (i < N_X4) {
    const float4 v = ((const float4*)x)[i];
    bf16x4 o;
    o.x = (__bf16)v.x; o.y = (__bf16)v.y; o.z = (__bf16)v.z; o.w = (__bf16)v.w;
    ((bf16x4*)xb)[i] = o;
  } else if (i < N_X4 + N_WIN4) {
    const int j = i - N_X4;
    const float s = (j < 262144) ? C_SCALE : 1.0f;   // first 1024 rows = Q
    const float4 v = ((const float4*)W_in)[j];
    bf16x4 o;
    o.x = (__bf16)(v.x * s); o.y = (__bf16)(v.y * s);
    o.z = (__bf16)(v.z * s); o.w = (__bf16)(v.w * s);
    ((bf16x4*)Winb)[j] = o;
  } else if (i < N_X4 + N_WIN4 + N_WOUT4) {
    const int j = i - N_X4 - N_WIN4;
    const float4 v = ((const float4*)W_out)[j];
    bf16x4 o;
    o.x = (__bf16)v.x; o.y = (__bf16)v.y; o.z = (__bf16)v.z; o.w = (__bf16)v.w;
    ((bf16x4*)Woutb)[j] = o;
  } else {
    const int j = i - N_X4 - N_WIN4 - N_WOUT4;   // 0..767
    const float s = (j < 256) ? C_SCALE : 1.0f;
    float4 v = ((const float4*)b_in)[j];
    v.x *= s; v.y *= s; v.z *= s; v.w *= s;
    ((float4*)bins)[j] = v;
  }
}

// ---------------------------------------------------------------- GEMM C = A @ B^T + bias
// 128x128 tile, BK=64, DOUBLE-BUFFERED LDS (2 x [128][64] per matrix, 64 KB).
// Pipelined 2-phase: stage tile kt+1 into buf^1 via gload_lds, compute
// buf[cur], ONE __syncthreads() per iter. XOR content swizzle via
// inverse-swizzled global source col + swizzled ds_read col (conflicts = 0,
// verified R6). T1 XCD block swizzle (nwg%8==0 bijection).
// MODE 0: fp32 out. MODE 2: qkv — Q/K cols (<2048) stored bf16 row-major,
// V cols (>=2048) stored transposed into Vt[(b*16+h)*64+dh][s] (8B packed).
template <int MODE>
__global__ __launch_bounds__(256) void gemm_bt(
    const __bf16* __restrict__ A, const __bf16* __restrict__ B,
    const float* __restrict__ bias, void* __restrict__ Cout,
    __bf16* __restrict__ Vt, int M, int N, int K) {
  __shared__ __bf16 As[2][128 * 64];
  __shared__ __bf16 Bs[2][128 * 64];
  const int tid = threadIdx.x;
  const int wave = tid >> 6, lane = tid & 63;
  const int quad = lane >> 4, l15 = lane & 15;
  const int wm = (wave & 1) * 64, wn = (wave >> 1) * 64;

  // T1: XCD-contiguous block swizzle (bijective since nwg % 8 == 0)
  const int nwg = (int)(gridDim.x * gridDim.y);
  int f = (int)(blockIdx.y * gridDim.x + blockIdx.x);
  f = (f & 7) * (nwg >> 3) + (f >> 3);
  const int bx = f % (int)gridDim.x;
  const int by = f / (int)gridDim.x;
  const long row0 = (long)by * 128;
  const long col0 = (long)bx * 128;

  floatx4 acc[4][4] = {};

  const int sr = tid >> 3;                         // 0..31
  const int swz = 8 * ((tid & 7) ^ (sr & 7));      // source col (elements)
  const __bf16* ga = A + (row0 + sr) * (long)K + swz;
  const __bf16* gb = B + (col0 + sr) * (long)K + swz;
  const int ld = tid * 8;                          // linear LDS dest (elems)
  const int rswz = (l15 & 7) * 8;                  // read-side xor (elements)

  // prologue: tile 0 -> buf 0
#pragma unroll
  for (int c = 0; c < 4; ++c) {
    gload_lds16(ga + (long)(32 * c) * K, &As[0][ld + c * 2048]);
    gload_lds16(gb + (long)(32 * c) * K, &Bs[0][ld + c * 2048]);
  }
  ga += 64; gb += 64;
  __syncthreads();

  const int nt = K >> 6;
  int cur = 0;
  for (int kt = 0; kt < nt; ++kt) {
    if (kt + 1 < nt) {                // stage next tile into buf^1
#pragma unroll
      for (int c = 0; c < 4; ++c) {
        gload_lds16(ga + (long)(32 * c) * K, &As[cur ^ 1][ld + c * 2048]);
        gload_lds16(gb + (long)(32 * c) * K, &Bs[cur ^ 1][ld + c * 2048]);
      }
      ga += 64; gb += 64;
    }

#pragma unroll
    for (int kh = 0; kh < 2; ++kh) {
      const int kc = (kh * 32 + quad * 8) ^ rswz;
      bf16x8 af[4], bfr[4];
#pragma unroll
      for (int i = 0; i < 4; ++i)
        af[i] = *(const bf16x8*)(&As[cur][(wm + i * 16 + l15) * 64 + kc]);
#pragma unroll
      for (int j = 0; j < 4; ++j)
        bfr[j] = *(const bf16x8*)(&Bs[cur][(wn + j * 16 + l15) * 64 + kc]);
#pragma unroll
      for (int i = 0; i < 4; ++i)
#pragma unroll
        for (int j = 0; j < 4; ++j)
          acc[i][j] = MFMA16(af[i], bfr[j], acc[i][j]);
    }
    __syncthreads();                  // fences staged writes + buf reads
    cur ^= 1;
  }

#pragma unroll
  for (int i = 0; i < 4; ++i) {
    const long r0 = row0 + wm + i * 16 + quad * 4;
#pragma unroll
    for (int j = 0; j < 4; ++j) {
      const long c = col0 + wn + j * 16 + l15;
      const float bv = bias[c];
      if (MODE == 0) {
#pragma unroll
        for (int reg = 0; reg < 4; ++reg)
          ((float*)Cout)[(r0 + reg) * (long)N + c] = acc[i][j][reg] + bv;
      } else {
        if (c < 2048) {
#pragma unroll
          for (int reg = 0; reg < 4; ++reg)
            ((__bf16*)Cout)[(r0 + reg) * (long)N + c] =
                (__bf16)(acc[i][j][reg] + bv);
        } else {
          const int cc = (int)c - 2048;
          const int hh = cc >> 6, dh = cc & 63;
          const int bb = (int)(r0 >> 11), s = (int)(r0 & 2047);
          bf16x4 pk;
#pragma unroll
          for (int reg = 0; reg < 4; ++reg)
            pk[reg] = (__bf16)(acc[i][j][reg] + bv);
          *(bf16x4*)(Vt + ((long)(bb * 16 + hh) * 64 + dh) * 2048 + s) = pk;
        }
      }
    }
  }
}

// ---------------------------------------------------------------- flash attention
// Block = (swizzled x, h, b), 256 thr (4 waves), grid 1024 = 4 blocks/CU.
// K/V staged via global_load_lds into linear [64][64] LDS (32 KB total),
// content-swizzled via inverse-XOR on the GLOBAL source col; reads use the
// XOR formulas. Loads for tile kt+1 issue at iter-top into buf^1;
// __syncthreads()'s vmcnt(0) fences completion. Verified R13 (<70 us).
// S^T = K@Q^T; P^T = exp2(S) unnormalized (verified R8); denom via
// ones-MFMA; O^T += V^T-frag @ P^T.
__global__ __launch_bounds__(256, 4) void flash_attn(
    const __bf16* __restrict__ qkv,   // [8192][3072]
    const __bf16* __restrict__ Vt,    // [64][64][2048]
    __bf16* __restrict__ Out) {       // [8192][1024]
  constexpr int S = 2048;
  const int h = blockIdx.y, b = blockIdx.z;
  const int x = (int)(blockIdx.x + 5 * blockIdx.z + 3 * blockIdx.y) & 15;
  const int qtA = x, qtB = 31 - x;
  const int kmaxA = qtA + 1;
  const int kmax  = qtB + 1;          // wall iterations (17..32)

  __shared__ __bf16 Ks[2][64 * 64];
  __shared__ __bf16 Vs[2][64 * 64];   // [dh][key]

  const int tid = threadIdx.x, wave = tid >> 6, lane = tid & 63;
  const int quad = lane >> 4, l15 = lane & 15;

  // Q frags (B-operand of the S^T MFMA: n=l15, k=quad*8+j)
  bf16x8 qf[2][2];
  {
    const long qrA = (long)(b * S + qtA * 64 + wave * 16 + l15) * 3072 + h * 64;
    const long qrB = (long)(b * S + qtB * 64 + wave * 16 + l15) * 3072 + h * 64;
    qf[0][0] = *(const bf16x8*)(qkv + qrA + quad * 8);
    qf[0][1] = *(const bf16x8*)(qkv + qrA + 32 + quad * 8);
    qf[1][0] = *(const bf16x8*)(qkv + qrB + quad * 8);
    qf[1][1] = *(const bf16x8*)(qkv + qrB + 32 + quad * 8);
  }

  bf16x4 ones4;
#pragma unroll
  for (int j = 0; j < 4; ++j) ones4[j] = (__bf16)1.0f;

  floatx4 oA[4] = {}, oB[4] = {};     // O^T C-layout
  floatx4 lA = {0.f, 0.f, 0.f, 0.f}, lB = {0.f, 0.f, 0.f, 0.f};

  // staging (global_load_lds): thread covers rows r and r+32, 16B chunk
  // tid&7; LDS dest linear tid*16B; source col inverse-swizzled.
  const int r = tid >> 3;                          // 0..31
  const int csw = 8 * ((tid & 7) ^ (r & 7));       // source col (elements)
  const __bf16* ka = qkv + ((long)(b * S) + r) * 3072 + 1024 + h * 64 + csw;
  const __bf16* va = Vt + ((long)(b * 16 + h) * 64 + r) * S + csw;

  // prologue: tile 0 -> buf0
  gload_lds16(ka,                 &Ks[0][tid * 8]);
  gload_lds16(ka + 32 * 3072,     &Ks[0][tid * 8 + 32 * 64]);
  gload_lds16(va,                 &Vs[0][tid * 8]);
  gload_lds16(va + 32 * (long)S,  &Vs[0][tid * 8 + 32 * 64]);
  const __bf16* kan = ka + 64 * 3072;  // tile kt+1 source
  const __bf16* van = va + 64;
  __syncthreads();

  const int rs = (l15 & 7) * 8;       // read-side xor (elements)

  for (int kt = 0; kt < kmax; ++kt) {
    const int cur = kt & 1;
    if (kt + 1 < kmax) {              // issue next tile into buf^1
      gload_lds16(kan,                &Ks[cur ^ 1][tid * 8]);
      gload_lds16(kan + 32 * 3072,    &Ks[cur ^ 1][tid * 8 + 32 * 64]);
      gload_lds16(van,                &Vs[cur ^ 1][tid * 8]);
      gload_lds16(van + 32 * (long)S, &Vs[cur ^ 1][tid * 8 + 32 * 64]);
      kan += 64 * 3072; van += 64;
    }

    const bool actA = (kt < kmaxA);
    const bool partA = (kt == qtA);
    const bool partB = (kt == qtB);

    // S^T = K @ Q^T for both sets, sharing each K fragment read
    floatx4 svA[4], svB[4];
    __builtin_amdgcn_s_setprio(1);
#pragma unroll
    for (int nb = 0; nb < 4; ++nb) {
      const int krow = (nb * 16 + l15) * 64;
      const bf16x8 k0 = *(const bf16x8*)(&Ks[cur][krow + ((quad * 8) ^ rs)]);
      const bf16x8 k1 = *(const bf16x8*)(&Ks[cur][krow + ((32 + quad * 8) ^ rs)]);
      if (actA) {
        floatx4 z = {0.f, 0.f, 0.f, 0.f};
        z = MFMA16(k0, qf[0][0], z);
        z = MFMA16(k1, qf[0][1], z);
        svA[nb] = z;
      }
      {
        floatx4 z = {0.f, 0.f, 0.f, 0.f};
        z = MFMA16(k0, qf[1][0], z);
        z = MFMA16(k1, qf[1][1], z);
        svB[nb] = z;
      }
    }
    __builtin_amdgcn_s_setprio(0);

    // causal mask on S^T: key = kt*64+nb*16+quad*4+r, q = qt*64+wave*16+l15
    if (partA) {
      const int qg = qtA * 64 + wave * 16 + l15;
#pragma unroll
      for (int nb = 0; nb < 4; ++nb) {
        const int key0 = kt * 64 + nb * 16 + quad * 4;
#pragma unroll
        for (int rr = 0; rr < 4; ++rr)
          if (key0 + rr > qg) svA[nb][rr] = -1.0e30f;
      }
    }
    if (partB) {
      const int qg = qtB * 64 + wave * 16 + l15;
#pragma unroll
      for (int nb = 0; nb < 4; ++nb) {
        const int key0 = kt * 64 + nb * 16 + quad * 4;
#pragma unroll
        for (int rr = 0; rr < 4; ++rr)
          if (key0 + rr > qg) svB[nb][rr] = -1.0e30f;
      }
    }

    // P^T = exp2(S^T) packed bf16x4 (unnormalized; denominator absorbs it)
    bf16x4 pfA[4], pfB[4];
    if (actA) {
#pragma unroll
      for (int nb = 0; nb < 4; ++nb)
#pragma unroll
        for (int rr = 0; rr < 4; ++rr)
          pfA[nb][rr] = (__bf16)fast_exp2(svA[nb][rr]);
#pragma unroll
      for (int c = 0; c < 4; ++c) lA = mfma_k16(ones4, pfA[c], lA);
    }
    {
#pragma unroll
      for (int nb = 0; nb < 4; ++nb)
#pragma unroll
        for (int rr = 0; rr < 4; ++rr)
          pfB[nb][rr] = (__bf16)fast_exp2(svB[nb][rr]);
#pragma unroll
      for (int c = 0; c < 4; ++c) lB = mfma_k16(ones4, pfB[c], lB);
    }

    // O^T += V^T @ P^T (A = V^T-frag b64 from LDS, shared; B = P^T registers)
    __builtin_amdgcn_s_setprio(1);
#pragma unroll
    for (int mb = 0; mb < 4; ++mb) {
      const int vrow = (mb * 16 + l15) * 64;
#pragma unroll
      for (int c = 0; c < 4; ++c) {
        const int vcol = c * 16 + quad * 4;
        const int vphys = (((vcol >> 3) ^ (l15 & 7)) << 3) + (vcol & 7);
        const bf16x4 vf = *(const bf16x4*)(&Vs[cur][vrow + vphys]);
        if (actA) oA[mb] = mfma_k16(vf, pfA[c], oA[mb]);
        oB[mb] = mfma_k16(vf, pfB[c], oB[mb]);
      }
    }
    __builtin_amdgcn_s_setprio(0);
    __syncthreads();                  // vmcnt(0) drain fences next-tile loads
  }

  // epilogue: lane holds dh = mb*16+quad*4+r at q = l15; denom = lX[0]
  {
    const float inv = 1.f / lA[0];
    const long row = (long)(b * S + qtA * 64 + wave * 16 + l15);
#pragma unroll
    for (int mb = 0; mb < 4; ++mb) {
      bf16x4 pk;
#pragma unroll
      for (int rr = 0; rr < 4; ++rr) pk[rr] = (__bf16)(oA[mb][rr] * inv);
      *(bf16x4*)(Out + row * 1024 + h * 64 + mb * 16 + quad * 4) = pk;
    }
  }
  {
    const float inv = 1.f / lB[0];
    const long row = (long)(b * S + qtB * 64 + wave * 16 + l15);
#pragma unroll
    for (int mb = 0; mb < 4; ++mb) {
      bf16x4 pk;
#pragma unroll
      for (int rr = 0; rr < 4; ++rr) pk[rr] = (__bf16)(oB[mb][rr] * inv);
      *(bf16x4*)(Out + row * 1024 + h * 64 + mb * 16 + quad * 4) = pk;
    }
  }
}

// ---------------------------------------------------------------- launch
extern "C" void kernel_launch(void* const* d_in, const int* in_sizes, int n_in,
                              void* d_out, int out_size, void* d_ws, size_t ws_size,
                              hipStream_t stream) {
  const float* x     = (const float*)d_in[0];
  const float* W_in  = (const float*)d_in[1];
  const float* b_in  = (const float*)d_in[2];
  const float* W_out = (const float*)d_in[3];
  const float* b_out = (const float*)d_in[4];

  const int BS = 4 * 2048;   // 8192 rows
  const int D = 1024, N3 = 3072;

  char* w = (char*)d_ws;
  __bf16* xb    = (__bf16*)w;  w += (size_t)BS * D * 2;        // 16 MiB
  __bf16* Winb  = (__bf16*)w;  w += (size_t)N3 * D * 2;        //  6 MiB
  __bf16* Woutb = (__bf16*)w;  w += (size_t)D * D * 2;         //  2 MiB
  __bf16* qkvb  = (__bf16*)w;  w += (size_t)BS * N3 * 2;       // 48 MiB
  __bf16* Vtb   = (__bf16*)w;  w += (size_t)64 * 64 * 2048 * 2;// 16 MiB
  __bf16* attnb = (__bf16*)w;  w += (size_t)BS * D * 2;        // 16 MiB
  float*  bins  = (float*)w;   w += (size_t)N3 * 4;            // 12 KiB

  const int castN = N_X4 + N_WIN4 + N_WOUT4 + N_B4;            // 3146496
  cast_fused<<<dim3(castN / 256), 256, 0, stream>>>(
      x, W_in, W_out, b_in, xb, Winb, Woutb, bins);

  gemm_bt<2><<<dim3(N3 / 128, BS / 128), 256, 0, stream>>>(
      xb, Winb, bins, (void*)qkvb, Vtb, BS, N3, D);

  flash_attn<<<dim3(16, 16, 4), 256, 0, stream>>>(qkvb, Vtb, attnb);

  gemm_bt<0><<<dim3(D / 128, BS / 128), 256, 0, stream>>>(
      attnb, Woutb, b_out, d_out, nullptr, BS, D, D);
}

// Round 16
// 244.084 us; speedup vs baseline: 1.1111x; 1.0094x over previous
//
#include <hip/hip_runtime.h>
#include <hip/hip_bf16.h>
#include <cstdint>

// Problem: x[4,2048,1024] fp32; qkv = x@W_in^T+b_in; 16-head causal attention
// (dh=64); out = attn@W_out^T + b_out -> fp32 [4,2048,1024].
// Verified: gemm BK=64 + both-sides XOR swizzle (conflicts 0) + T1 XCD
// swizzle (70.5 us); flash global_load_lds staging + stage-before-compute +
// single barrier (R13, <70 us); bare v_exp_f32; no-M_STATIC exp.
// R23 NEUTRAL (measured R14): gemm dbuf 64KB halved occupancy (26->19.5%),
// offsetting pipeline gain (m99/m100 precedent).
// R24: revert gemm to R22 single-buffer (70.5); cast -> grid-stride 2048
// blocks (G11). Flash unchanged. R25: identical resubmit (broker timeout).

typedef float  floatx4  __attribute__((ext_vector_type(4)));
typedef __bf16 bf16x8   __attribute__((ext_vector_type(8)));
typedef __bf16 bf16x4   __attribute__((ext_vector_type(4)));
typedef short  shortx4  __attribute__((ext_vector_type(4)));
typedef unsigned int   uint32x2 __attribute__((ext_vector_type(2)));
typedef unsigned short ushortx8 __attribute__((ext_vector_type(8)));

#define MFMA16(a,b,c) __builtin_amdgcn_mfma_f32_16x16x32_bf16(a, b, c, 0, 0, 0)

// 16x16x16 bf16 MFMA (K=16). Selected only in the device pass (host stub).
__device__ __forceinline__ floatx4 mfma_k16(bf16x4 a, bf16x4 b, floatx4 c) {
#if defined(__HIP_DEVICE_COMPILE__)
#if __has_builtin(__builtin_amdgcn_mfma_f32_16x16x16_bf16)
  return __builtin_amdgcn_mfma_f32_16x16x16_bf16(a, b, c, 0, 0, 0);
#elif __has_builtin(__builtin_amdgcn_mfma_f32_16x16x16bf16_1k)
  return __builtin_amdgcn_mfma_f32_16x16x16bf16_1k(
      __builtin_bit_cast(shortx4, a), __builtin_bit_cast(shortx4, b), c, 0, 0, 0);
#else
  floatx4 d;
  asm("v_mfma_f32_16x16x16_bf16 %0, %1, %2, %3"
      : "=v"(d)
      : "v"(__builtin_bit_cast(uint32x2, a)),
        "v"(__builtin_bit_cast(uint32x2, b)), "v"(c));
  return d;
#endif
#else
  (void)a; (void)b;
  return c;  // host stub
#endif
}

// Bare hardware exp2 (D = 2^S0).
__device__ __forceinline__ float fast_exp2(float x) {
#if defined(__HIP_DEVICE_COMPILE__)
#if __has_builtin(__builtin_amdgcn_exp2f)
  return __builtin_amdgcn_exp2f(x);
#else
  float r;
  asm("v_exp_f32 %0, %1" : "=v"(r) : "v"(x));
  return r;
#endif
#else
  return x;  // host stub
#endif
}

#define C_SCALE 0.18033688011112042f  /* (1/sqrt(64)) * log2(e) */

__device__ __forceinline__ void gload_lds16(const void* g, void* l) {
  __builtin_amdgcn_global_load_lds(
      (__attribute__((address_space(1))) void*)(g),
      (__attribute__((address_space(3))) void*)(l), 16, 0, 0);
}

// ---------------------------------------------------------------- fused casts
#define N_X4    2097152   /* 8192*1024/4 */
#define N_WIN4  786432    /* 3072*1024/4 */
#define N_WOUT4 262144    /* 1024*1024/4 */
#define N_B4    768       /* 3072/4      */
#define CAST_TOTAL (N_X4 + N_WIN4 + N_WOUT4 + N_B4)
__global__ __launch_bounds__(256) void cast_fused(
    const float* __restrict__ x, const float* __restrict__ W_in,
    const float* __restrict__ W_out, const float* __restrict__ b_in,
    __bf16* __restrict__ xb, __bf16* __restrict__ Winb,
    __bf16* __restrict__ Woutb, float* __restrict__ bins) {
  const int stride = (int)(gridDim.x * 256);
  for (int i = blockIdx.x * 256 + threadIdx.x; i < CAST_TOTAL; i += stride) {
    if (i < N_X4) {
      const float4 v = ((const float4*)x)[i];
      bf16x4 o;
      o.x = (__bf16)v.x; o.y = (__bf16)v.y; o.z = (__bf16)v.z; o.w = (__bf16)v.w;
      ((bf16x4*)xb)[i] = o;
    } else if (i < N_X4 + N_WIN4) {
      const int j = i - N_X4;
      const float s = (j < 262144) ? C_SCALE : 1.0f;   // first 1024 rows = Q
      const float4 v = ((const float4*)W_in)[j];
      bf16x4 o;
      o.x = (__bf16)(v.x * s); o.y = (__bf16)(v.y * s);
      o.z = (__bf16)(v.z * s); o.w = (__bf16)(v.w * s);
      ((bf16x4*)Winb)[j] = o;
    } else if (i < N_X4 + N_WIN4 + N_WOUT4) {
      const int j = i - N_X4 - N_WIN4;
      const float4 v = ((const float4*)W_out)[j];
      bf16x4 o;
      o.x = (__bf16)v.x; o.y = (__bf16)v.y; o.z = (__bf16)v.z; o.w = (__bf16)v.w;
      ((bf16x4*)Woutb)[j] = o;
    } else {
      const int j = i - N_X4 - N_WIN4 - N_WOUT4;   // 0..767
      const float s = (j < 256) ? C_SCALE : 1.0f;
      float4 v = ((const float4*)b_in)[j];
      v.x *= s; v.y *= s; v.z *= s; v.w *= s;
      ((float4*)bins)[j] = v;
    }
  }
}

// ---------------------------------------------------------------- GEMM C = A @ B^T + bias
// 128x128 tile, BK=64 (32 MFMA per barrier pair), single-buffer [128][64]
// per matrix (32 KB; 26% occupancy measured). XOR content swizzle via
// inverse-swizzled global source col + swizzled ds_read col (conflicts = 0,
// verified R6). T1 XCD block swizzle (nwg%8==0 bijection). Verified 70.5 us
// (R13); R14's explicit dbuf was neutral (occupancy loss offset the overlap;
// m99/m100 precedent).
// MODE 0: fp32 out. MODE 2: qkv — Q/K cols (<2048) stored bf16 row-major,
// V cols (>=2048) stored transposed into Vt[(b*16+h)*64+dh][s] (8B packed).
template <int MODE>
__global__ __launch_bounds__(256) void gemm_bt(
    const __bf16* __restrict__ A, const __bf16* __restrict__ B,
    const float* __restrict__ bias, void* __restrict__ Cout,
    __bf16* __restrict__ Vt, int M, int N, int K) {
  __shared__ __bf16 As[128 * 64];
  __shared__ __bf16 Bs[128 * 64];
  const int tid = threadIdx.x;
  const int wave = tid >> 6, lane = tid & 63;
  const int quad = lane >> 4, l15 = lane & 15;
  const int wm = (wave & 1) * 64, wn = (wave >> 1) * 64;

  // T1: XCD-contiguous block swizzle (bijective since nwg % 8 == 0)
  const int nwg = (int)(gridDim.x * gridDim.y);
  int f = (int)(blockIdx.y * gridDim.x + blockIdx.x);
  f = (f & 7) * (nwg >> 3) + (f >> 3);
  const int bx = f % (int)gridDim.x;
  const int by = f / (int)gridDim.x;
  const long row0 = (long)by * 128;
  const long col0 = (long)bx * 128;

  floatx4 acc[4][4] = {};

  const int sr = tid >> 3;                         // 0..31
  const int swz = 8 * ((tid & 7) ^ (sr & 7));      // source col (elements)
  const __bf16* ga = A + (row0 + sr) * (long)K + swz;
  const __bf16* gb = B + (col0 + sr) * (long)K + swz;
  __bf16* lA = As + tid * 8;
  __bf16* lB = Bs + tid * 8;
  const int rswz = (l15 & 7) * 8;                  // read-side xor (elements)

  for (int k0 = 0; k0 < K; k0 += 64) {
#pragma unroll
    for (int c = 0; c < 4; ++c) {
      gload_lds16(ga + (long)(32 * c) * K, lA + c * 2048);
      gload_lds16(gb + (long)(32 * c) * K, lB + c * 2048);
    }
    ga += 64; gb += 64;
    __syncthreads();

#pragma unroll
    for (int kh = 0; kh < 2; ++kh) {
      const int kc = (kh * 32 + quad * 8) ^ rswz;
      bf16x8 af[4], bfr[4];
#pragma unroll
      for (int i = 0; i < 4; ++i)
        af[i] = *(const bf16x8*)(As + (wm + i * 16 + l15) * 64 + kc);
#pragma unroll
      for (int j = 0; j < 4; ++j)
        bfr[j] = *(const bf16x8*)(Bs + (wn + j * 16 + l15) * 64 + kc);
#pragma unroll
      for (int i = 0; i < 4; ++i)
#pragma unroll
        for (int j = 0; j < 4; ++j)
          acc[i][j] = MFMA16(af[i], bfr[j], acc[i][j]);
    }
    __syncthreads();
  }

#pragma unroll
  for (int i = 0; i < 4; ++i) {
    const long r0 = row0 + wm + i * 16 + quad * 4;
#pragma unroll
    for (int j = 0; j < 4; ++j) {
      const long c = col0 + wn + j * 16 + l15;
      const float bv = bias[c];
      if (MODE == 0) {
#pragma unroll
        for (int reg = 0; reg < 4; ++reg)
          ((float*)Cout)[(r0 + reg) * (long)N + c] = acc[i][j][reg] + bv;
      } else {
        if (c < 2048) {
#pragma unroll
          for (int reg = 0; reg < 4; ++reg)
            ((__bf16*)Cout)[(r0 + reg) * (long)N + c] =
                (__bf16)(acc[i][j][reg] + bv);
        } else {
          const int cc = (int)c - 2048;
          const int hh = cc >> 6, dh = cc & 63;
          const int bb = (int)(r0 >> 11), s = (int)(r0 & 2047);
          bf16x4 pk;
#pragma unroll
          for (int reg = 0; reg < 4; ++reg)
            pk[reg] = (__bf16)(acc[i][j][reg] + bv);
          *(bf16x4*)(Vt + ((long)(bb * 16 + hh) * 64 + dh) * 2048 + s) = pk;
        }
      }
    }
  }
}

// ---------------------------------------------------------------- flash attention
// Block = (swizzled x, h, b), 256 thr (4 waves), grid 1024 = 4 blocks/CU.
// K/V staged via global_load_lds into linear [64][64] LDS (32 KB total),
// content-swizzled via inverse-XOR on the GLOBAL source col; reads use the
// XOR formulas. Loads for tile kt+1 issue at iter-top into buf^1;
// __syncthreads()'s vmcnt(0) fences completion. Verified R13 (<70 us).
// S^T = K@Q^T; P^T = exp2(S) unnormalized (verified R8); denom via
// ones-MFMA; O^T += V^T-frag @ P^T.
__global__ __launch_bounds__(256, 4) void flash_attn(
    const __bf16* __restrict__ qkv,   // [8192][3072]
    const __bf16* __restrict__ Vt,    // [64][64][2048]
    __bf16* __restrict__ Out) {       // [8192][1024]
  constexpr int S = 2048;
  const int h = blockIdx.y, b = blockIdx.z;
  const int x = (int)(blockIdx.x + 5 * blockIdx.z + 3 * blockIdx.y) & 15;
  const int qtA = x, qtB = 31 - x;
  const int kmaxA = qtA + 1;
  const int kmax  = qtB + 1;          // wall iterations (17..32)

  __shared__ __bf16 Ks[2][64 * 64];
  __shared__ __bf16 Vs[2][64 * 64];   // [dh][key]

  const int tid = threadIdx.x, wave = tid >> 6, lane = tid & 63;
  const int quad = lane >> 4, l15 = lane & 15;

  // Q frags (B-operand of the S^T MFMA: n=l15, k=quad*8+j)
  bf16x8 qf[2][2];
  {
    const long qrA = (long)(b * S + qtA * 64 + wave * 16 + l15) * 3072 + h * 64;
    const long qrB = (long)(b * S + qtB * 64 + wave * 16 + l15) * 3072 + h * 64;
    qf[0][0] = *(const bf16x8*)(qkv + qrA + quad * 8);
    qf[0][1] = *(const bf16x8*)(qkv + qrA + 32 + quad * 8);
    qf[1][0] = *(const bf16x8*)(qkv + qrB + quad * 8);
    qf[1][1] = *(const bf16x8*)(qkv + qrB + 32 + quad * 8);
  }

  bf16x4 ones4;
#pragma unroll
  for (int j = 0; j < 4; ++j) ones4[j] = (__bf16)1.0f;

  floatx4 oA[4] = {}, oB[4] = {};     // O^T C-layout
  floatx4 lA = {0.f, 0.f, 0.f, 0.f}, lB = {0.f, 0.f, 0.f, 0.f};

  // staging (global_load_lds): thread covers rows r and r+32, 16B chunk
  // tid&7; LDS dest linear tid*16B; source col inverse-swizzled.
  const int r = tid >> 3;                          // 0..31
  const int csw = 8 * ((tid & 7) ^ (r & 7));       // source col (elements)
  const __bf16* ka = qkv + ((long)(b * S) + r) * 3072 + 1024 + h * 64 + csw;
  const __bf16* va = Vt + ((long)(b * 16 + h) * 64 + r) * S + csw;

  // prologue: tile 0 -> buf0
  gload_lds16(ka,                 &Ks[0][tid * 8]);
  gload_lds16(ka + 32 * 3072,     &Ks[0][tid * 8 + 32 * 64]);
  gload_lds16(va,                 &Vs[0][tid * 8]);
  gload_lds16(va + 32 * (long)S,  &Vs[0][tid * 8 + 32 * 64]);
  const __bf16* kan = ka + 64 * 3072;  // tile kt+1 source
  const __bf16* van = va + 64;
  __syncthreads();

  const int rs = (l15 & 7) * 8;       // read-side xor (elements)

  for (int kt = 0; kt < kmax; ++kt) {
    const int cur = kt & 1;
    if (kt + 1 < kmax) {              // issue next tile into buf^1
      gload_lds16(kan,                &Ks[cur ^ 1][tid * 8]);
      gload_lds16(kan + 32 * 3072,    &Ks[cur ^ 1][tid * 8 + 32 * 64]);
      gload_lds16(van,                &Vs[cur ^ 1][tid * 8]);
      gload_lds16(van + 32 * (long)S, &Vs[cur ^ 1][tid * 8 + 32 * 64]);
      kan += 64 * 3072; van += 64;
    }

    const bool actA = (kt < kmaxA);
    const bool partA = (kt == qtA);
    const bool partB = (kt == qtB);

    // S^T = K @ Q^T for both sets, sharing each K fragment read
    floatx4 svA[4], svB[4];
    __builtin_amdgcn_s_setprio(1);
#pragma unroll
    for (int nb = 0; nb < 4; ++nb) {
      const int krow = (nb * 16 + l15) * 64;
      const bf16x8 k0 = *(const bf16x8*)(&Ks[cur][krow + ((quad * 8) ^ rs)]);
      const bf16x8 k1 = *(const bf16x8*)(&Ks[cur][krow + ((32 + quad * 8) ^ rs)]);
      if (actA) {
        floatx4 z = {0.f, 0.f, 0.f, 0.f};
        z = MFMA16(k0, qf[0][0], z);
        z = MFMA16(k1, qf[0][1], z);
        svA[nb] = z;
      }
      {
        floatx4 z = {0.f, 0.f, 0.f, 0.f};
        z = MFMA16(k0, qf[1][0], z);
        z = MFMA16(k1, qf[1][1], z);
        svB[nb] = z;
      }
    }
    __builtin_amdgcn_s_setprio(0);

    // causal mask on S^T: key = kt*64+nb*16+quad*4+r, q = qt*64+wave*16+l15
    if (partA) {
      const int qg = qtA * 64 + wave * 16 + l15;
#pragma unroll
      for (int nb = 0; nb < 4; ++nb) {
        const int key0 = kt * 64 + nb * 16 + quad * 4;
#pragma unroll
        for (int rr = 0; rr < 4; ++rr)
          if (key0 + rr > qg) svA[nb][rr] = -1.0e30f;
      }
    }
    if (partB) {
      const int qg = qtB * 64 + wave * 16 + l15;
#pragma unroll
      for (int nb = 0; nb < 4; ++nb) {
        const int key0 = kt * 64 + nb * 16 + quad * 4;
#pragma unroll
        for (int rr = 0; rr < 4; ++rr)
          if (key0 + rr > qg) svB[nb][rr] = -1.0e30f;
      }
    }

    // P^T = exp2(S^T) packed bf16x4 (unnormalized; denominator absorbs it)
    bf16x4 pfA[4], pfB[4];
    if (actA) {
#pragma unroll
      for (int nb = 0; nb < 4; ++nb)
#pragma unroll
        for (int rr = 0; rr < 4; ++rr)
          pfA[nb][rr] = (__bf16)fast_exp2(svA[nb][rr]);
#pragma unroll
      for (int c = 0; c < 4; ++c) lA = mfma_k16(ones4, pfA[c], lA);
    }
    {
#pragma unroll
      for (int nb = 0; nb < 4; ++nb)
#pragma unroll
        for (int rr = 0; rr < 4; ++rr)
          pfB[nb][rr] = (__bf16)fast_exp2(svB[nb][rr]);
#pragma unroll
      for (int c = 0; c < 4; ++c) lB = mfma_k16(ones4, pfB[c], lB);
    }

    // O^T += V^T @ P^T (A = V^T-frag b64 from LDS, shared; B = P^T registers)
    __builtin_amdgcn_s_setprio(1);
#pragma unroll
    for (int mb = 0; mb < 4; ++mb) {
      const int vrow = (mb * 16 + l15) * 64;
#pragma unroll
      for (int c = 0; c < 4; ++c) {
        const int vcol = c * 16 + quad * 4;
        const int vphys = (((vcol >> 3) ^ (l15 & 7)) << 3) + (vcol & 7);
        const bf16x4 vf = *(const bf16x4*)(&Vs[cur][vrow + vphys]);
        if (actA) oA[mb] = mfma_k16(vf, pfA[c], oA[mb]);
        oB[mb] = mfma_k16(vf, pfB[c], oB[mb]);
      }
    }
    __builtin_amdgcn_s_setprio(0);
    __syncthreads();                  // vmcnt(0) drain fences next-tile loads
  }

  // epilogue: lane holds dh = mb*16+quad*4+r at q = l15; denom = lX[0]
  {
    const float inv = 1.f / lA[0];
    const long row = (long)(b * S + qtA * 64 + wave * 16 + l15);
#pragma unroll
    for (int mb = 0; mb < 4; ++mb) {
      bf16x4 pk;
#pragma unroll
      for (int rr = 0; rr < 4; ++rr) pk[rr] = (__bf16)(oA[mb][rr] * inv);
      *(bf16x4*)(Out + row * 1024 + h * 64 + mb * 16 + quad * 4) = pk;
    }
  }
  {
    const float inv = 1.f / lB[0];
    const long row = (long)(b * S + qtB * 64 + wave * 16 + l15);
#pragma unroll
    for (int mb = 0; mb < 4; ++mb) {
      bf16x4 pk;
#pragma unroll
      for (int rr = 0; rr < 4; ++rr) pk[rr] = (__bf16)(oB[mb][rr] * inv);
      *(bf16x4*)(Out + row * 1024 + h * 64 + mb * 16 + quad * 4) = pk;
    }
  }
}

// ---------------------------------------------------------------- launch
extern "C" void kernel_launch(void* const* d_in, const int* in_sizes, int n_in,
                              void* d_out, int out_size, void* d_ws, size_t ws_size,
                              hipStream_t stream) {
  const float* x     = (const float*)d_in[0];
  const float* W_in  = (const float*)d_in[1];
  const float* b_in  = (const float*)d_in[2];
  const float* W_out = (const float*)d_in[3];
  const float* b_out = (const float*)d_in[4];

  const int BS = 4 * 2048;   // 8192 rows
  const int D = 1024, N3 = 3072;

  char* w = (char*)d_ws;
  __bf16* xb    = (__bf16*)w;  w += (size_t)BS * D * 2;        // 16 MiB
  __bf16* Winb  = (__bf16*)w;  w += (size_t)N3 * D * 2;        //  6 MiB
  __bf16* Woutb = (__bf16*)w;  w += (size_t)D * D * 2;         //  2 MiB
  __bf16* qkvb  = (__bf16*)w;  w += (size_t)BS * N3 * 2;       // 48 MiB
  __bf16* Vtb   = (__bf16*)w;  w += (size_t)64 * 64 * 2048 * 2;// 16 MiB
  __bf16* attnb = (__bf16*)w;  w += (size_t)BS * D * 2;        // 16 MiB
  float*  bins  = (float*)w;   w += (size_t)N3 * 4;            // 12 KiB

  cast_fused<<<dim3(2048), 256, 0, stream>>>(
      x, W_in, W_out, b_in, xb, Winb, Woutb, bins);

  gemm_bt<2><<<dim3(N3 / 128, BS / 128), 256, 0, stream>>>(
      xb, Winb, bins, (void*)qkvb, Vtb, BS, N3, D);

  flash_attn<<<dim3(16, 16, 4), 256, 0, stream>>>(qkvb, Vtb, attnb);

  gemm_bt<0><<<dim3(D / 128, BS / 128), 256, 0, stream>>>(
      attnb, Woutb, b_out, d_out, nullptr, BS, D, D);
}